// Round 12
// baseline (137.931 us; speedup 1.0000x reference)
//
#include <hip/hip_runtime.h>

#define N_NODES 50000
#define N_EDGES 800000
#define IN_CH   128
#define HID_CH  512
#define OUT_CH  256

// 128-node dst-buckets, fixed capacity (mean 2048, sigma~45, cap 4096)
#define BKT_SHIFT 7
#define BKT_NODES 128
#define NBKT ((N_NODES + BKT_NODES - 1) / BKT_NODES)        // 391
#define BCAP 4096
#define P1_EPT    8
#define P1_EPB    (512 * P1_EPT)                            // 4096 edges/block
#define P1_BLOCKS ((N_EDGES + P1_EPB - 1) / P1_EPB)         // 196
#define CVT_BLOCKS 3125                                     // 1.6M float4 / 512

typedef __attribute__((ext_vector_type(8))) short bf16x8;
typedef __attribute__((ext_vector_type(4))) float f32x4;

static __device__ __forceinline__ ushort f2bf(float f) {
    uint u = __float_as_uint(f);
    uint r = u + 0x7fffu + ((u >> 16) & 1u);   // RNE; inputs are finite
    return (ushort)(r >> 16);
}

// ---------------------------------------------------------------------------
// W12t[j][i] = sum_k W1[i][k]*W2[k][j]  (bf16, TRANSPOSED [256][128])
// b2[j] = sum_k b1[k]*W2[k][j]          (f32)
// 33 blocks x 1024 thr; block 0 also zeroes bucketcnt.
// ---------------------------------------------------------------------------
__global__ __launch_bounds__(1024) void build_w12(const float* __restrict__ W1,
                                                  const float* __restrict__ b1,
                                                  const float* __restrict__ W2,
                                                  ushort* __restrict__ W12t,
                                                  float* __restrict__ b2,
                                                  int* __restrict__ bucketcnt) {
    __shared__ float a[4][HID_CH];                 // 8 KB
    __shared__ float red[4][4][256];               // 16 KB  [kc][row][j]
    const int t   = threadIdx.x;
    const int j   = t & 255;
    const int kc  = t >> 8;                        // 0..3
    const int blk = blockIdx.x;
    if (blk == 0 && t < NBKT) bucketcnt[t] = 0;

    const bool bias = (blk == 32);
    if (!bias) {
        const int i0 = blk * 4;
        for (int lin = t; lin < 4 * HID_CH; lin += 1024)
            a[lin >> 9][lin & 511] = W1[(size_t)(i0 + (lin >> 9)) * HID_CH + (lin & 511)];
    } else {
        for (int lin = t; lin < HID_CH; lin += 1024) a[0][lin] = b1[lin];
    }
    __syncthreads();

    float acc[4] = {0.f, 0.f, 0.f, 0.f};
    const int k0 = kc * 128;
    if (!bias) {
        for (int k = k0; k < k0 + 128; ++k) {
            const float w = W2[(size_t)k * OUT_CH + j];
#pragma unroll
            for (int r = 0; r < 4; ++r) acc[r] = fmaf(a[r][k], w, acc[r]);
        }
    } else {
        for (int k = k0; k < k0 + 128; ++k)
            acc[0] = fmaf(a[0][k], W2[(size_t)k * OUT_CH + j], acc[0]);
    }
#pragma unroll
    for (int r = 0; r < 4; ++r) red[kc][r][j] = acc[r];
    __syncthreads();
    if (kc == 0) {
#pragma unroll
        for (int r = 0; r < 4; ++r) {
            const float s = red[0][r][j] + red[1][r][j] + red[2][r][j] + red[3][r][j];
            if (!bias) W12t[(size_t)j * IN_CH + blk * 4 + r] = f2bf(s);
            else if (r == 0) b2[j] = s;
        }
    }
}

// ---------------------------------------------------------------------------
// FUSED: blocks 0..3124 convert x->xb (bf16); blocks 3125..3320 partition
// edges into 391 fixed-capacity dst-buckets (128 nodes each).
// Packed word: b<<23 | src<<7 | (dst&127).
// ---------------------------------------------------------------------------
__global__ __launch_bounds__(512) void cvt_part(const float* __restrict__ x,
                                                ushort* __restrict__ xb,
                                                const int* __restrict__ ei,
                                                int* __restrict__ bucketcnt,
                                                uint* __restrict__ pairbuf) {
    __shared__ uint stage[P1_EPB];                 // 16 KB (partition branch only)
    __shared__ int cnt[512], off[512], cur[512], base[512];
    const int t = threadIdx.x;

    if (blockIdx.x < CVT_BLOCKS) {
        const int gid = blockIdx.x * 512 + t;      // 3125*512 == 1.6M exactly
        const float4 v = *(const float4*)(x + (size_t)gid * 4);
        ushort4 o;
        o.x = f2bf(v.x); o.y = f2bf(v.y); o.z = f2bf(v.z); o.w = f2bf(v.w);
        *(ushort4*)(xb + (size_t)gid * 4) = o;
        return;
    }

    const int e0 = (blockIdx.x - CVT_BLOCKS) * P1_EPB;

    cnt[t] = 0;
    __syncthreads();

    uint pk[P1_EPT];
    int  bk[P1_EPT];
    bool vl[P1_EPT];
#pragma unroll
    for (int i = 0; i < P1_EPT; ++i) {
        const int e = e0 + i * 512 + t;
        vl[i] = (e < N_EDGES);
        if (vl[i]) {
            const int src = ei[e];
            const int dst = ei[N_EDGES + e];
            const int b = dst >> BKT_SHIFT;
            bk[i] = b;
            pk[i] = ((uint)b << 23) | ((uint)src << 7) | (uint)(dst & (BKT_NODES - 1));
            atomicAdd(&cnt[b], 1);
        }
    }
    __syncthreads();

    // exclusive scan of cnt[0..511] -> off
    off[t] = cnt[t];
    __syncthreads();
#pragma unroll
    for (int d = 1; d < 512; d <<= 1) {
        const int u = (t >= d) ? off[t - d] : 0;
        __syncthreads();
        off[t] += u;
        __syncthreads();
    }
    off[t] -= cnt[t];                              // exclusive
    cur[t] = off[t];
    if (t < NBKT && cnt[t] > 0)
        base[t] = t * BCAP + atomicAdd(&bucketcnt[t], cnt[t]);
    __syncthreads();

#pragma unroll
    for (int i = 0; i < P1_EPT; ++i)
        if (vl[i]) {
            const int lp = atomicAdd(&cur[bk[i]], 1);
            stage[lp] = pk[i];
        }
    __syncthreads();

    const int TOT = off[511] + cnt[511];
    for (int idx = t; idx < TOT; idx += 512) {
        const uint p = stage[idx];
        const int b = (int)(p >> 23);
        pairbuf[base[b] + (idx - off[b])] = p;
    }
}

// ---------------------------------------------------------------------------
// MEGA-FUSED per-bucket kernel: one block = one 128-node bucket.
// Phase 1: counting-sort bucket edges -> LDS srcloc (no global CSR).
// Phase 2: 8 waves x 16 nodes register-accum gather -> swizzled LDS A-tile.
// Phase 3: MFMA (A from LDS, B = W12t direct from L2) -> nontemporal out.
// LDS ~51 KB; no aggb/srcidx global roundtrips.
// ---------------------------------------------------------------------------
__global__ __launch_bounds__(512) void fused_bucket(const ushort* __restrict__ xb,
                                                    const int* __restrict__ bucketcnt,
                                                    const uint* __restrict__ pairbuf,
                                                    const ushort* __restrict__ w12t,
                                                    const float* __restrict__ b2,
                                                    float* __restrict__ out) {
    __shared__ int  srcloc[BCAP];                  // 16 KB sorted srcs
    __shared__ uint atile[BKT_NODES * 64];         // 32 KB bf16 A-tile (swizzled)
    __shared__ int  cnt[128], off[128], cur[128], locrow[129];

    const int b = blockIdx.x;
    const int t = threadIdx.x;
    const int ne = bucketcnt[b];
    const uint* eb = pairbuf + (size_t)b * BCAP;
    const int nbase = b * BKT_NODES;
    const int nloc = (nbase + BKT_NODES <= N_NODES) ? BKT_NODES : (N_NODES - nbase);

    // ---- Phase 1: bucket-local counting sort into LDS ----
    if (t < 128) cnt[t] = 0;
    __syncthreads();
    for (int i = t; i < ne; i += 512)
        atomicAdd(&cnt[eb[i] & (BKT_NODES - 1)], 1);
    __syncthreads();
    if (t < 128) off[t] = cnt[t];
    __syncthreads();
#pragma unroll
    for (int d = 1; d < 128; d <<= 1) {
        int u = 0;
        if (t < 128 && t >= d) u = off[t - d];
        __syncthreads();
        if (t < 128 && t >= d) off[t] += u;
        __syncthreads();
    }
    if (t < 128) {
        off[t] -= cnt[t];
        cur[t] = off[t];
        locrow[t] = off[t];
        if (t == 0) locrow[128] = ne;
    }
    __syncthreads();
    for (int i = t; i < ne; i += 512) {
        const uint p = eb[i];
        const int ln = (int)(p & (BKT_NODES - 1));
        const int pos = atomicAdd(&cur[ln], 1);
        srcloc[pos] = (int)((p >> 7) & 0xFFFFu);
    }
    __syncthreads();

    // ---- Phase 2: gather (register accum) -> swizzled A-tile ----
    const int lane = t & 63;
    const int wv   = t >> 6;
    const uint* xrow = (const uint*)xb;            // 64 uints per node row
    for (int ln = wv; ln < nloc; ln += 8) {
        const uint self = xrow[(size_t)(nbase + ln) * 64 + lane];
        float ax = __uint_as_float(self << 16);
        float ay = __uint_as_float(self & 0xffff0000u);
        int e = locrow[ln];
        const int end = locrow[ln + 1];
        for (; e + 8 <= end; e += 8) {
            uint v[8];
#pragma unroll
            for (int i = 0; i < 8; ++i) {
                const int s = srcloc[e + i];       // LDS broadcast
                v[i] = xrow[(size_t)s * 64 + lane];
            }
#pragma unroll
            for (int i = 0; i < 8; ++i) {
                ax += __uint_as_float(v[i] << 16);
                ay += __uint_as_float(v[i] & 0xffff0000u);
            }
        }
        for (; e < end; ++e) {
            const uint v = xrow[(size_t)srcloc[e] * 64 + lane];
            ax += __uint_as_float(v << 16); ay += __uint_as_float(v & 0xffff0000u);
        }
        // swizzled write: word=lane, chunk=lane>>2, slot=chunk^(ln&7)
        const int slot = (lane >> 2) ^ (ln & 7);
        atile[ln * 64 + slot * 4 + (lane & 3)] =
            ((uint)f2bf(ay) << 16) | (uint)f2bf(ax);
    }
    __syncthreads();

    // ---- Phase 3: MFMA. A from LDS (swizzled), B from global (L2-hot). ----
    const int rbl  = (wv >> 1) * 32;               // local row quarter
    const int cbase = (wv & 1) * 128;              // col half
    const int l15 = lane & 15;
    const int oct = lane >> 4;

    f32x4 acc[2][8];
#pragma unroll
    for (int m = 0; m < 2; ++m)
#pragma unroll
        for (int n = 0; n < 8; ++n)
            acc[m][n] = (f32x4){0.f, 0.f, 0.f, 0.f};

#pragma unroll
    for (int kk = 0; kk < 4; ++kk) {               // k = kk*32 + oct*8 + j
        bf16x8 afr[2];
#pragma unroll
        for (int m = 0; m < 2; ++m) {
            const int row = rbl + m * 16 + l15;    // local row
            const int slot = (kk * 4 + oct) ^ (row & 7);
            afr[m] = *(const bf16x8*)((const char*)atile + row * 256 + slot * 16);
        }
#pragma unroll
        for (int n = 0; n < 8; ++n) {
            const int col = cbase + n * 16 + l15;
            const bf16x8 bfr = *(const bf16x8*)(w12t + (size_t)col * IN_CH
                                                + kk * 32 + oct * 8);
#pragma unroll
            for (int m = 0; m < 2; ++m)
                acc[m][n] = __builtin_amdgcn_mfma_f32_16x16x32_bf16(
                    afr[m], bfr, acc[m][n], 0, 0, 0);
        }
    }

#pragma unroll
    for (int m = 0; m < 2; ++m) {
        const int row0 = nbase + rbl + m * 16 + oct * 4;
#pragma unroll
        for (int n = 0; n < 8; ++n) {
            const int col = cbase + n * 16 + l15;
            const float bias = b2[col];
#pragma unroll
            for (int r = 0; r < 4; ++r) {
                const int row = row0 + r;
                if (row < N_NODES)
                    __builtin_nontemporal_store(acc[m][n][r] + bias,
                                                &out[(size_t)row * OUT_CH + col]);
            }
        }
    }
}

// ---------------------------------------------------------------------------
extern "C" void kernel_launch(void* const* d_in, const int* in_sizes, int n_in,
                              void* d_out, int out_size, void* d_ws, size_t ws_size,
                              hipStream_t stream) {
    const float* x  = (const float*)d_in[0];
    const int*   ei = (const int*)d_in[1];      // [2, N_EDGES] int32
    const float* W1 = (const float*)d_in[2];
    const float* b1 = (const float*)d_in[3];
    const float* W2 = (const float*)d_in[4];
    float* out = (float*)d_out;

    // workspace layout (bytes)
    char* ws = (char*)d_ws;
    ushort* xb        = (ushort*)(ws + 0);               // 12,800,000
    ushort* W12t      = (ushort*)(ws + 12800000);        //     65,536
    float*  b2        = (float*) (ws + 12865536);        //      1,024
    uint*   pairbuf   = (uint*)  (ws + 12866560);        //  6,406,144 (391*4096*4)
    int*    bucketcnt = (int*)   (ws + 19272704);        //      1,564  -> ~19.3 MB

    // 1) collapse MLP -> bf16 W12^T + f32 b2 (+ zero bucketcnt)
    build_w12<<<dim3(33), dim3(1024), 0, stream>>>(W1, b1, W2, W12t, b2, bucketcnt);

    // 2) FUSED: x -> bf16 || partition edges into dst-buckets
    cvt_part<<<dim3(CVT_BLOCKS + P1_BLOCKS), dim3(512), 0, stream>>>(
        x, xb, ei, bucketcnt, pairbuf);

    // 3) MEGA-FUSED: per-bucket sort + gather + MFMA GEMM -> out
    fused_bucket<<<dim3(NBKT), dim3(512), 0, stream>>>(
        xb, bucketcnt, pairbuf, W12t, b2, out);
}

// Round 13
// 114.891 us; speedup vs baseline: 1.2005x; 1.2005x over previous
//
#include <hip/hip_runtime.h>

#define N_NODES 50000
#define N_EDGES 800000
#define IN_CH   128
#define HID_CH  512
#define OUT_CH  256

// 128-node dst-buckets, fixed capacity (mean 2048, sigma~45, cap 4096)
#define BKT_SHIFT 7
#define BKT_NODES 128
#define NBKT ((N_NODES + BKT_NODES - 1) / BKT_NODES)        // 391
#define BCAP 4096
#define P1_EPT    8
#define P1_EPB    (512 * P1_EPT)                            // 4096 edges/block
#define P1_BLOCKS ((N_EDGES + P1_EPB - 1) / P1_EPB)         // 196
#define CVT_BLOCKS 3125                                     // 1.6M float4 / 512

typedef __attribute__((ext_vector_type(8))) short bf16x8;
typedef __attribute__((ext_vector_type(4))) float f32x4;

static __device__ __forceinline__ ushort f2bf(float f) {
    uint u = __float_as_uint(f);
    uint r = u + 0x7fffu + ((u >> 16) & 1u);   // RNE; inputs are finite
    return (ushort)(r >> 16);
}

// ---------------------------------------------------------------------------
// W12t[j][i] = sum_k W1[i][k]*W2[k][j]  (bf16, TRANSPOSED [256][128])
// b2[j] = sum_k b1[k]*W2[k][j]          (f32)
// 33 blocks x 1024 thr; block 0 also zeroes bucketcnt.
// ---------------------------------------------------------------------------
__global__ __launch_bounds__(1024) void build_w12(const float* __restrict__ W1,
                                                  const float* __restrict__ b1,
                                                  const float* __restrict__ W2,
                                                  ushort* __restrict__ W12t,
                                                  float* __restrict__ b2,
                                                  int* __restrict__ bucketcnt) {
    __shared__ float a[4][HID_CH];                 // 8 KB
    __shared__ float red[4][4][256];               // 16 KB  [kc][row][j]
    const int t   = threadIdx.x;
    const int j   = t & 255;
    const int kc  = t >> 8;                        // 0..3
    const int blk = blockIdx.x;
    if (blk == 0 && t < NBKT) bucketcnt[t] = 0;

    const bool bias = (blk == 32);
    if (!bias) {
        const int i0 = blk * 4;
        for (int lin = t; lin < 4 * HID_CH; lin += 1024)
            a[lin >> 9][lin & 511] = W1[(size_t)(i0 + (lin >> 9)) * HID_CH + (lin & 511)];
    } else {
        for (int lin = t; lin < HID_CH; lin += 1024) a[0][lin] = b1[lin];
    }
    __syncthreads();

    float acc[4] = {0.f, 0.f, 0.f, 0.f};
    const int k0 = kc * 128;
    if (!bias) {
        for (int k = k0; k < k0 + 128; ++k) {
            const float w = W2[(size_t)k * OUT_CH + j];
#pragma unroll
            for (int r = 0; r < 4; ++r) acc[r] = fmaf(a[r][k], w, acc[r]);
        }
    } else {
        for (int k = k0; k < k0 + 128; ++k)
            acc[0] = fmaf(a[0][k], W2[(size_t)k * OUT_CH + j], acc[0]);
    }
#pragma unroll
    for (int r = 0; r < 4; ++r) red[kc][r][j] = acc[r];
    __syncthreads();
    if (kc == 0) {
#pragma unroll
        for (int r = 0; r < 4; ++r) {
            const float s = red[0][r][j] + red[1][r][j] + red[2][r][j] + red[3][r][j];
            if (!bias) W12t[(size_t)j * IN_CH + blk * 4 + r] = f2bf(s);
            else if (r == 0) b2[j] = s;
        }
    }
}

// ---------------------------------------------------------------------------
// FUSED: blocks 0..3124 convert x->xb (bf16); blocks 3125..3320 partition
// edges into 391 fixed-capacity dst-buckets (128 nodes each).
// Packed word: b<<23 | src<<7 | (dst&127).
// ---------------------------------------------------------------------------
__global__ __launch_bounds__(512) void cvt_part(const float* __restrict__ x,
                                                ushort* __restrict__ xb,
                                                const int* __restrict__ ei,
                                                int* __restrict__ bucketcnt,
                                                uint* __restrict__ pairbuf) {
    __shared__ uint stage[P1_EPB];                 // 16 KB (partition branch only)
    __shared__ int cnt[512], off[512], cur[512], base[512];
    const int t = threadIdx.x;

    if (blockIdx.x < CVT_BLOCKS) {
        const int gid = blockIdx.x * 512 + t;      // 3125*512 == 1.6M exactly
        const float4 v = *(const float4*)(x + (size_t)gid * 4);
        ushort4 o;
        o.x = f2bf(v.x); o.y = f2bf(v.y); o.z = f2bf(v.z); o.w = f2bf(v.w);
        *(ushort4*)(xb + (size_t)gid * 4) = o;
        return;
    }

    const int e0 = (blockIdx.x - CVT_BLOCKS) * P1_EPB;

    cnt[t] = 0;
    __syncthreads();

    uint pk[P1_EPT];
    int  bk[P1_EPT];
    bool vl[P1_EPT];
#pragma unroll
    for (int i = 0; i < P1_EPT; ++i) {
        const int e = e0 + i * 512 + t;
        vl[i] = (e < N_EDGES);
        if (vl[i]) {
            const int src = ei[e];
            const int dst = ei[N_EDGES + e];
            const int b = dst >> BKT_SHIFT;
            bk[i] = b;
            pk[i] = ((uint)b << 23) | ((uint)src << 7) | (uint)(dst & (BKT_NODES - 1));
            atomicAdd(&cnt[b], 1);
        }
    }
    __syncthreads();

    // exclusive scan of cnt[0..511] -> off
    off[t] = cnt[t];
    __syncthreads();
#pragma unroll
    for (int d = 1; d < 512; d <<= 1) {
        const int u = (t >= d) ? off[t - d] : 0;
        __syncthreads();
        off[t] += u;
        __syncthreads();
    }
    off[t] -= cnt[t];                              // exclusive
    cur[t] = off[t];
    if (t < NBKT && cnt[t] > 0)
        base[t] = t * BCAP + atomicAdd(&bucketcnt[t], cnt[t]);
    __syncthreads();

#pragma unroll
    for (int i = 0; i < P1_EPT; ++i)
        if (vl[i]) {
            const int lp = atomicAdd(&cur[bk[i]], 1);
            stage[lp] = pk[i];
        }
    __syncthreads();

    const int TOT = off[511] + cnt[511];
    for (int idx = t; idx < TOT; idx += 512) {
        const uint p = stage[idx];
        const int b = (int)(p >> 23);
        pairbuf[base[b] + (idx - off[b])] = p;
    }
}

// ---------------------------------------------------------------------------
// Per-bucket local counting sort: pairbuf bucket -> bucket-local CSR.
// 391 blocks x 256 threads, 128-wide scan.
// ---------------------------------------------------------------------------
__global__ __launch_bounds__(256) void bucket_fill2(const uint* __restrict__ pairbuf,
                                                    const int* __restrict__ bucketcnt,
                                                    int* __restrict__ locrow,
                                                    int* __restrict__ srcidx) {
    __shared__ int cnt[128], off[128], cur[128];
    const int b = blockIdx.x;
    const int t = threadIdx.x;
    const int ne = bucketcnt[b];
    const uint* eb = pairbuf + (size_t)b * BCAP;

    if (t < 128) cnt[t] = 0;
    __syncthreads();
    for (int i = t; i < ne; i += 256)
        atomicAdd(&cnt[eb[i] & (BKT_NODES - 1)], 1);
    __syncthreads();

    if (t < 128) off[t] = cnt[t];
    __syncthreads();
#pragma unroll
    for (int d = 1; d < 128; d <<= 1) {
        int u = 0;
        if (t < 128 && t >= d) u = off[t - d];
        __syncthreads();
        if (t < 128 && t >= d) off[t] += u;
        __syncthreads();
    }
    if (t < 128) {
        off[t] -= cnt[t];
        cur[t] = off[t];
        locrow[b * (BKT_NODES + 1) + t] = off[t];
        if (t == 0) locrow[b * (BKT_NODES + 1) + BKT_NODES] = ne;
    }
    __syncthreads();

    for (int i = t; i < ne; i += 256) {
        const uint p = eb[i];
        const int ln  = (int)(p & (BKT_NODES - 1));
        const int src = (int)((p >> 7) & 0xFFFFu);
        const int pos = atomicAdd(&cur[ln], 1);
        srcidx[(size_t)b * BCAP + pos] = src;
    }
}

// ---------------------------------------------------------------------------
// FUSED gather+GEMM at gather-granularity: block = 16 nodes, 256 thr, 4 waves.
// Phase A: wave wv gathers nodes wv*4..wv*4+3 (register accum, bucket-local
// CSR) -> swizzled 4 KB LDS A-tile. Phase B: 16x256 MFMA tile, A from LDS,
// B = W12t from L2 (64 KB hot), nontemporal f32 out. 3125 blocks -> 12500
// waves (~8/SIMD). Kills the aggb roundtrip + one launch.
// ---------------------------------------------------------------------------
__global__ __launch_bounds__(256) void gather_gemm(const ushort* __restrict__ xb,
                                                   const int* __restrict__ locrow,
                                                   const int* __restrict__ srcidx,
                                                   const ushort* __restrict__ w12t,
                                                   const float* __restrict__ b2,
                                                   float* __restrict__ out) {
    __shared__ uint atile[16 * 64];                // 4 KB (swizzled bf16 rows)
    const int t    = threadIdx.x;
    const int lane = t & 63;
    const int wv   = t >> 6;                       // 0..3
    const int tile0 = blockIdx.x * 16;             // first node (3125*16=50000)
    const int b     = blockIdx.x >> 3;             // bucket (16-tile never crosses)
    const int lrb   = b * (BKT_NODES + 1);
    const int lnb   = (blockIdx.x & 7) * 16;       // local-node base in bucket
    const uint* xrow = (const uint*)xb;            // 64 uints per node row
    const int* sb = srcidx + (size_t)b * BCAP;

    // ---- Phase A: gather 4 nodes per wave, register accumulation ----
#pragma unroll
    for (int i = 0; i < 4; ++i) {
        const int ln16 = wv * 4 + i;               // row in tile (0..15)
        const int node = tile0 + ln16;
        const uint self = xrow[(size_t)node * 64 + lane];
        float ax = __uint_as_float(self << 16);
        float ay = __uint_as_float(self & 0xffff0000u);
        int e = locrow[lrb + lnb + ln16];
        const int end = locrow[lrb + lnb + ln16 + 1];
        for (; e + 8 <= end; e += 8) {
            uint v[8];
#pragma unroll
            for (int k = 0; k < 8; ++k) {
                const int s = sb[e + k];
                v[k] = xrow[(size_t)s * 64 + lane];
            }
#pragma unroll
            for (int k = 0; k < 8; ++k) {
                ax += __uint_as_float(v[k] << 16);
                ay += __uint_as_float(v[k] & 0xffff0000u);
            }
        }
        for (; e < end; ++e) {
            const uint v = xrow[(size_t)sb[e] * 64 + lane];
            ax += __uint_as_float(v << 16); ay += __uint_as_float(v & 0xffff0000u);
        }
        // swizzled store: chunk = lane>>2 -> slot = chunk ^ (row&7)
        const int slot = (lane >> 2) ^ (ln16 & 7);
        atile[ln16 * 64 + slot * 4 + (lane & 3)] =
            ((uint)f2bf(ay) << 16) | (uint)f2bf(ax);
    }
    __syncthreads();

    // ---- Phase B: MFMA 16 rows x 256 cols; wave wv owns cols wv*64..+63 ----
    const int l15 = lane & 15;
    const int oct = lane >> 4;
    const int cbase = wv * 64;

    f32x4 acc[4];
#pragma unroll
    for (int n = 0; n < 4; ++n) acc[n] = (f32x4){0.f, 0.f, 0.f, 0.f};

#pragma unroll
    for (int kk = 0; kk < 4; ++kk) {               // k = kk*32 + oct*8 + j
        const int slotA = (kk * 4 + oct) ^ (l15 & 7);
        const bf16x8 afr =
            *(const bf16x8*)((const char*)atile + l15 * 256 + slotA * 16);
#pragma unroll
        for (int n = 0; n < 4; ++n) {
            const int col = cbase + n * 16 + l15;
            const bf16x8 bfr = *(const bf16x8*)(w12t + (size_t)col * IN_CH
                                                + kk * 32 + oct * 8);
            acc[n] = __builtin_amdgcn_mfma_f32_16x16x32_bf16(afr, bfr, acc[n], 0, 0, 0);
        }
    }

    // epilogue: D col = lane&15, row = oct*4 + r
#pragma unroll
    for (int n = 0; n < 4; ++n) {
        const int col = cbase + n * 16 + l15;
        const float bias = b2[col];
#pragma unroll
        for (int r = 0; r < 4; ++r) {
            const int row = tile0 + oct * 4 + r;   // always < 50000
            __builtin_nontemporal_store(acc[n][r] + bias,
                                        &out[(size_t)row * OUT_CH + col]);
        }
    }
}

// ---------------------------------------------------------------------------
extern "C" void kernel_launch(void* const* d_in, const int* in_sizes, int n_in,
                              void* d_out, int out_size, void* d_ws, size_t ws_size,
                              hipStream_t stream) {
    const float* x  = (const float*)d_in[0];
    const int*   ei = (const int*)d_in[1];      // [2, N_EDGES] int32
    const float* W1 = (const float*)d_in[2];
    const float* b1 = (const float*)d_in[3];
    const float* W2 = (const float*)d_in[4];
    float* out = (float*)d_out;

    // workspace layout (bytes)
    char* ws = (char*)d_ws;
    ushort* xb        = (ushort*)(ws + 0);               // 12,800,000
    ushort* W12t      = (ushort*)(ws + 12800000);        //     65,536
    float*  b2        = (float*) (ws + 12865536);        //      1,024
    uint*   pairbuf   = (uint*)  (ws + 12866560);        //  6,406,144 (391*4096*4)
    int*    srcidx    = (int*)   (ws + 19272704);        //  6,406,144
    int*    locrow    = (int*)   (ws + 25678848);        //    201,756 (391*129*4)
    int*    bucketcnt = (int*)   (ws + 25880604);        //      1,564  -> ~25.9 MB

    // 1) collapse MLP -> bf16 W12^T + f32 b2 (+ zero bucketcnt)
    build_w12<<<dim3(33), dim3(1024), 0, stream>>>(W1, b1, W2, W12t, b2, bucketcnt);

    // 2) FUSED: x -> bf16 || partition edges into dst-buckets
    cvt_part<<<dim3(CVT_BLOCKS + P1_BLOCKS), dim3(512), 0, stream>>>(
        x, xb, ei, bucketcnt, pairbuf);

    // 3) per-bucket local counting sort -> bucket-local CSR
    bucket_fill2<<<dim3(NBKT), dim3(256), 0, stream>>>(pairbuf, bucketcnt,
                                                       locrow, srcidx);

    // 4) FUSED gather + MFMA GEMM -> out (no aggb roundtrip)
    gather_gemm<<<dim3(N_NODES / 16), dim3(256), 0, stream>>>(
        xb, locrow, srcidx, W12t, b2, out);
}

// Round 14
// 92.593 us; speedup vs baseline: 1.4897x; 1.2408x over previous
//
#include <hip/hip_runtime.h>

#define N_NODES 50000
#define N_EDGES 800000
#define IN_CH   128
#define HID_CH  512
#define OUT_CH  256

// 128-node dst-buckets, fixed capacity (mean 2048, sigma~45, cap 4096)
#define BKT_SHIFT 7
#define BKT_NODES 128
#define NBKT ((N_NODES + BKT_NODES - 1) / BKT_NODES)        // 391
#define BCAP 4096
#define P1_EPT    8
#define P1_EPB    (512 * P1_EPT)                            // 4096 edges/block
#define P1_BLOCKS ((N_EDGES + P1_EPB - 1) / P1_EPB)         // 196
#define CVT_BLOCKS 3125                                     // 1.6M float4 / 512

typedef __attribute__((ext_vector_type(8))) short bf16x8;
typedef __attribute__((ext_vector_type(4))) float f32x4;

static __device__ __forceinline__ ushort f2bf(float f) {
    uint u = __float_as_uint(f);
    uint r = u + 0x7fffu + ((u >> 16) & 1u);   // RNE; inputs are finite
    return (ushort)(r >> 16);
}

// ---------------------------------------------------------------------------
// W12t[j][i] = sum_k W1[i][k]*W2[k][j]  (bf16, TRANSPOSED [256][128])
// b2[j] = sum_k b1[k]*W2[k][j]          (f32)
// 33 blocks x 1024 thr; block 0 also zeroes bucketcnt.
// ---------------------------------------------------------------------------
__global__ __launch_bounds__(1024) void build_w12(const float* __restrict__ W1,
                                                  const float* __restrict__ b1,
                                                  const float* __restrict__ W2,
                                                  ushort* __restrict__ W12t,
                                                  float* __restrict__ b2,
                                                  int* __restrict__ bucketcnt) {
    __shared__ float a[4][HID_CH];                 // 8 KB
    __shared__ float red[4][4][256];               // 16 KB  [kc][row][j]
    const int t   = threadIdx.x;
    const int j   = t & 255;
    const int kc  = t >> 8;                        // 0..3
    const int blk = blockIdx.x;
    if (blk == 0 && t < NBKT) bucketcnt[t] = 0;

    const bool bias = (blk == 32);
    if (!bias) {
        const int i0 = blk * 4;
        for (int lin = t; lin < 4 * HID_CH; lin += 1024)
            a[lin >> 9][lin & 511] = W1[(size_t)(i0 + (lin >> 9)) * HID_CH + (lin & 511)];
    } else {
        for (int lin = t; lin < HID_CH; lin += 1024) a[0][lin] = b1[lin];
    }
    __syncthreads();

    float acc[4] = {0.f, 0.f, 0.f, 0.f};
    const int k0 = kc * 128;
    if (!bias) {
        for (int k = k0; k < k0 + 128; ++k) {
            const float w = W2[(size_t)k * OUT_CH + j];
#pragma unroll
            for (int r = 0; r < 4; ++r) acc[r] = fmaf(a[r][k], w, acc[r]);
        }
    } else {
        for (int k = k0; k < k0 + 128; ++k)
            acc[0] = fmaf(a[0][k], W2[(size_t)k * OUT_CH + j], acc[0]);
    }
#pragma unroll
    for (int r = 0; r < 4; ++r) red[kc][r][j] = acc[r];
    __syncthreads();
    if (kc == 0) {
#pragma unroll
        for (int r = 0; r < 4; ++r) {
            const float s = red[0][r][j] + red[1][r][j] + red[2][r][j] + red[3][r][j];
            if (!bias) W12t[(size_t)j * IN_CH + blk * 4 + r] = f2bf(s);
            else if (r == 0) b2[j] = s;
        }
    }
}

// ---------------------------------------------------------------------------
// FUSED: blocks 0..3124 convert x->xb (bf16); blocks 3125..3320 partition
// edges into 391 fixed-capacity dst-buckets (128 nodes each).
// Packed word: b<<23 | src<<7 | (dst&127).
// ---------------------------------------------------------------------------
__global__ __launch_bounds__(512) void cvt_part(const float* __restrict__ x,
                                                ushort* __restrict__ xb,
                                                const int* __restrict__ ei,
                                                int* __restrict__ bucketcnt,
                                                uint* __restrict__ pairbuf) {
    __shared__ uint stage[P1_EPB];                 // 16 KB (partition branch only)
    __shared__ int cnt[512], off[512], cur[512], base[512];
    const int t = threadIdx.x;

    if (blockIdx.x < CVT_BLOCKS) {
        const int gid = blockIdx.x * 512 + t;      // 3125*512 == 1.6M exactly
        const float4 v = *(const float4*)(x + (size_t)gid * 4);
        ushort4 o;
        o.x = f2bf(v.x); o.y = f2bf(v.y); o.z = f2bf(v.z); o.w = f2bf(v.w);
        *(ushort4*)(xb + (size_t)gid * 4) = o;
        return;
    }

    const int e0 = (blockIdx.x - CVT_BLOCKS) * P1_EPB;

    cnt[t] = 0;
    __syncthreads();

    uint pk[P1_EPT];
    int  bk[P1_EPT];
    bool vl[P1_EPT];
#pragma unroll
    for (int i = 0; i < P1_EPT; ++i) {
        const int e = e0 + i * 512 + t;
        vl[i] = (e < N_EDGES);
        if (vl[i]) {
            const int src = ei[e];
            const int dst = ei[N_EDGES + e];
            const int b = dst >> BKT_SHIFT;
            bk[i] = b;
            pk[i] = ((uint)b << 23) | ((uint)src << 7) | (uint)(dst & (BKT_NODES - 1));
            atomicAdd(&cnt[b], 1);
        }
    }
    __syncthreads();

    // exclusive scan of cnt[0..511] -> off
    off[t] = cnt[t];
    __syncthreads();
#pragma unroll
    for (int d = 1; d < 512; d <<= 1) {
        const int u = (t >= d) ? off[t - d] : 0;
        __syncthreads();
        off[t] += u;
        __syncthreads();
    }
    off[t] -= cnt[t];                              // exclusive
    cur[t] = off[t];
    if (t < NBKT && cnt[t] > 0)
        base[t] = t * BCAP + atomicAdd(&bucketcnt[t], cnt[t]);
    __syncthreads();

#pragma unroll
    for (int i = 0; i < P1_EPT; ++i)
        if (vl[i]) {
            const int lp = atomicAdd(&cur[bk[i]], 1);
            stage[lp] = pk[i];
        }
    __syncthreads();

    const int TOT = off[511] + cnt[511];
    for (int idx = t; idx < TOT; idx += 512) {
        const uint p = stage[idx];
        const int b = (int)(p >> 23);
        pairbuf[base[b] + (idx - off[b])] = p;
    }
}

// ---------------------------------------------------------------------------
// Per-bucket local counting sort: pairbuf bucket -> bucket-local CSR.
// srcidx stored as ushort (src < 65536): halves scattered-write window.
// ---------------------------------------------------------------------------
__global__ __launch_bounds__(256) void bucket_fill2(const uint* __restrict__ pairbuf,
                                                    const int* __restrict__ bucketcnt,
                                                    int* __restrict__ locrow,
                                                    ushort* __restrict__ srcidx) {
    __shared__ int cnt[128], off[128], cur[128];
    const int b = blockIdx.x;
    const int t = threadIdx.x;
    const int ne = bucketcnt[b];
    const uint* eb = pairbuf + (size_t)b * BCAP;

    if (t < 128) cnt[t] = 0;
    __syncthreads();
    for (int i = t; i < ne; i += 256)
        atomicAdd(&cnt[eb[i] & (BKT_NODES - 1)], 1);
    __syncthreads();

    if (t < 128) off[t] = cnt[t];
    __syncthreads();
#pragma unroll
    for (int d = 1; d < 128; d <<= 1) {
        int u = 0;
        if (t < 128 && t >= d) u = off[t - d];
        __syncthreads();
        if (t < 128 && t >= d) off[t] += u;
        __syncthreads();
    }
    if (t < 128) {
        off[t] -= cnt[t];
        cur[t] = off[t];
        locrow[b * (BKT_NODES + 1) + t] = off[t];
        if (t == 0) locrow[b * (BKT_NODES + 1) + BKT_NODES] = ne;
    }
    __syncthreads();

    for (int i = t; i < ne; i += 256) {
        const uint p = eb[i];
        const int ln  = (int)(p & (BKT_NODES - 1));
        const int pos = atomicAdd(&cur[ln], 1);
        srcidx[(size_t)b * BCAP + pos] = (ushort)((p >> 7) & 0xFFFFu);
    }
}

// ---------------------------------------------------------------------------
// Gather (bf16 rows, f32 accumulate): agg[n] = x[n] + sum_{e in in(n)} x[src]
// One wave per node, register accumulation (50K waves). Bucket-local CSR.
// ---------------------------------------------------------------------------
__global__ __launch_bounds__(256) void gather_bf16(const ushort* __restrict__ xb,
                                                   const int* __restrict__ locrow,
                                                   const ushort* __restrict__ srcidx,
                                                   ushort* __restrict__ aggb) {
    const int node = (int)((blockIdx.x * 256u + threadIdx.x) >> 6);
    const int lane = threadIdx.x & 63;
    if (node >= N_NODES) return;
    const int b  = node >> BKT_SHIFT;
    const int ln = node & (BKT_NODES - 1);
    const uint* xrow = (const uint*)xb;            // 64 uints per node row
    const uint self = xrow[(size_t)node * 64 + lane];
    float ax = __uint_as_float(self << 16);
    float ay = __uint_as_float(self & 0xffff0000u);
    int e = locrow[b * (BKT_NODES + 1) + ln];
    const int end = locrow[b * (BKT_NODES + 1) + ln + 1];
    const ushort* sb = srcidx + (size_t)b * BCAP;
    for (; e + 8 <= end; e += 8) {
        uint v[8];
#pragma unroll
        for (int i = 0; i < 8; ++i) {
            const int s = sb[e + i];
            v[i] = xrow[(size_t)s * 64 + lane];
        }
#pragma unroll
        for (int i = 0; i < 8; ++i) {
            ax += __uint_as_float(v[i] << 16);
            ay += __uint_as_float(v[i] & 0xffff0000u);
        }
    }
    for (; e < end; ++e) {
        const uint v = xrow[(size_t)sb[e] * 64 + lane];
        ax += __uint_as_float(v << 16); ay += __uint_as_float(v & 0xffff0000u);
    }
    const uint packed = ((uint)f2bf(ay) << 16) | (uint)f2bf(ax);
    ((uint*)aggb)[(size_t)node * 64 + lane] = packed;
}

// ---------------------------------------------------------------------------
// out[50000,256] = aggb @ W12 + b2 via bf16 MFMA 16x16x32.
// BM=128 -> 391 blocks (full CU coverage). Nontemporal stores.
// ---------------------------------------------------------------------------
__global__ __launch_bounds__(512) void mfma_gemm(const ushort* __restrict__ aggb,
                                                 const ushort* __restrict__ w12t,
                                                 const float* __restrict__ b2,
                                                 float* __restrict__ out) {
    __shared__ ushort bt[256 * 128];               // 64 KB
    const int tid = threadIdx.x;

#pragma unroll
    for (int it = 0; it < 8; ++it) {
        const int i = tid + it * 512;              // 0..4095
        const int n = i >> 4, s = i & 15;
        const uint4 v = *(const uint4*)(w12t + (size_t)i * 8);
        *(uint4*)(&bt[(n << 7) + ((s ^ (n & 7)) << 3)]) = v;
    }
    __syncthreads();

    const int lane = tid & 63;
    const int w    = tid >> 6;
    const int rbase = blockIdx.x * 128 + (w >> 1) * 32;
    const int cbase = (w & 1) * 128;
    const int l15 = lane & 15;
    const int oct = lane >> 4;

    f32x4 acc[2][8];
#pragma unroll
    for (int m = 0; m < 2; ++m)
#pragma unroll
        for (int n = 0; n < 8; ++n)
            acc[m][n] = (f32x4){0.f, 0.f, 0.f, 0.f};

#pragma unroll
    for (int kk = 0; kk < 4; ++kk) {               // k = kk*32 + oct*8 + j
        bf16x8 afr[2];
#pragma unroll
        for (int m = 0; m < 2; ++m) {
            int row = rbase + m * 16 + l15;
            row = row < N_NODES ? row : N_NODES - 1;
            afr[m] = *(const bf16x8*)(aggb + (size_t)row * IN_CH + kk * 32 + oct * 8);
        }
#pragma unroll
        for (int n = 0; n < 8; ++n) {
            const int col  = cbase + n * 16 + l15;
            const int slot = (kk * 4 + oct) ^ (col & 7);
            const bf16x8 bfr = *(const bf16x8*)(&bt[(col << 7) + (slot << 3)]);
#pragma unroll
            for (int m = 0; m < 2; ++m)
                acc[m][n] = __builtin_amdgcn_mfma_f32_16x16x32_bf16(
                    afr[m], bfr, acc[m][n], 0, 0, 0);
        }
    }

#pragma unroll
    for (int m = 0; m < 2; ++m) {
        const int row0 = rbase + m * 16 + oct * 4;
#pragma unroll
        for (int n = 0; n < 8; ++n) {
            const int col = cbase + n * 16 + l15;
            const float bias = b2[col];
#pragma unroll
            for (int r = 0; r < 4; ++r) {
                const int row = row0 + r;
                if (row < N_NODES)
                    __builtin_nontemporal_store(acc[m][n][r] + bias,
                                                &out[(size_t)row * OUT_CH + col]);
            }
        }
    }
}

// ---------------------------------------------------------------------------
extern "C" void kernel_launch(void* const* d_in, const int* in_sizes, int n_in,
                              void* d_out, int out_size, void* d_ws, size_t ws_size,
                              hipStream_t stream) {
    const float* x  = (const float*)d_in[0];
    const int*   ei = (const int*)d_in[1];      // [2, N_EDGES] int32
    const float* W1 = (const float*)d_in[2];
    const float* b1 = (const float*)d_in[3];
    const float* W2 = (const float*)d_in[4];
    float* out = (float*)d_out;

    // workspace layout (bytes)
    char* ws = (char*)d_ws;
    ushort* xb        = (ushort*)(ws + 0);               // 12,800,000
    ushort* aggb      = (ushort*)(ws + 12800000);        // 12,800,000
    uint*   pairbuf   = (uint*)  (ws + 12800000);        //  6,406,144 (aliases aggb;
                                                         //   dead before gather runs)
    ushort* W12t      = (ushort*)(ws + 25600000);        //     65,536
    float*  b2        = (float*) (ws + 25665536);        //      1,024
    ushort* srcidx    = (ushort*)(ws + 25666560);        //  3,203,072 (391*4096*2)
    int*    locrow    = (int*)   (ws + 28869632);        //    201,756 (391*129*4)
    int*    bucketcnt = (int*)   (ws + 29071388);        //      1,564  -> ~29.1 MB

    // 1) collapse MLP -> bf16 W12^T + f32 b2 (+ zero bucketcnt)
    build_w12<<<dim3(33), dim3(1024), 0, stream>>>(W1, b1, W2, W12t, b2, bucketcnt);

    // 2) FUSED: x -> bf16 || partition edges into dst-buckets
    cvt_part<<<dim3(CVT_BLOCKS + P1_BLOCKS), dim3(512), 0, stream>>>(
        x, xb, ei, bucketcnt, pairbuf);

    // 3) per-bucket local counting sort -> bucket-local CSR (ushort srcs)
    bucket_fill2<<<dim3(NBKT), dim3(256), 0, stream>>>(pairbuf, bucketcnt,
                                                       locrow, srcidx);

    // 4) gather (residual folded): aggb[n] = x[n] + sum x[src]   (bf16)
    gather_bf16<<<dim3(N_NODES * 64 / 256), dim3(256), 0, stream>>>(
        xb, locrow, srcidx, aggb);

    // 5) out = aggb @ W12 + b2   (bf16 MFMA)
    mfma_gemm<<<dim3((N_NODES + 127) / 128), dim3(512), 0, stream>>>(
        aggb, W12t, b2, out);
}

// Round 15
// 86.436 us; speedup vs baseline: 1.5958x; 1.0712x over previous
//
#include <hip/hip_runtime.h>

#define N_NODES 50000
#define N_EDGES 800000
#define IN_CH   128
#define HID_CH  512
#define OUT_CH  256

// 128-node dst-buckets, fixed capacity (mean 2048, sigma~45, cap 4096)
#define BKT_SHIFT 7
#define BKT_NODES 128
#define NBKT ((N_NODES + BKT_NODES - 1) / BKT_NODES)        // 391
#define BCAP 4096
#define P1_EPT    8
#define P1_EPB    (512 * P1_EPT)                            // 4096 edges/block
#define P1_BLOCKS ((N_EDGES + P1_EPB - 1) / P1_EPB)         // 196
#define CVT_BLOCKS 3125                                     // 1.6M float4 / 512

typedef __attribute__((ext_vector_type(8))) short bf16x8;
typedef __attribute__((ext_vector_type(4))) float f32x4;

static __device__ __forceinline__ ushort f2bf(float f) {
    uint u = __float_as_uint(f);
    uint r = u + 0x7fffu + ((u >> 16) & 1u);   // RNE; inputs are finite
    return (ushort)(r >> 16);
}

// ---------------------------------------------------------------------------
// W12t[j][i] = sum_k W1[i][k]*W2[k][j]  (bf16, TRANSPOSED [256][128])
// b2[j] = sum_k b1[k]*W2[k][j]          (f32)
// 33 blocks x 1024 thr; block 0 also zeroes bucketcnt.
// ---------------------------------------------------------------------------
__global__ __launch_bounds__(1024) void build_w12(const float* __restrict__ W1,
                                                  const float* __restrict__ b1,
                                                  const float* __restrict__ W2,
                                                  ushort* __restrict__ W12t,
                                                  float* __restrict__ b2,
                                                  int* __restrict__ bucketcnt) {
    __shared__ float a[4][HID_CH];                 // 8 KB
    __shared__ float red[4][4][256];               // 16 KB  [kc][row][j]
    const int t   = threadIdx.x;
    const int j   = t & 255;
    const int kc  = t >> 8;                        // 0..3
    const int blk = blockIdx.x;
    if (blk == 0 && t < NBKT) bucketcnt[t] = 0;

    const bool bias = (blk == 32);
    if (!bias) {
        const int i0 = blk * 4;
        for (int lin = t; lin < 4 * HID_CH; lin += 1024)
            a[lin >> 9][lin & 511] = W1[(size_t)(i0 + (lin >> 9)) * HID_CH + (lin & 511)];
    } else {
        for (int lin = t; lin < HID_CH; lin += 1024) a[0][lin] = b1[lin];
    }
    __syncthreads();

    float acc[4] = {0.f, 0.f, 0.f, 0.f};
    const int k0 = kc * 128;
    if (!bias) {
        for (int k = k0; k < k0 + 128; ++k) {
            const float w = W2[(size_t)k * OUT_CH + j];
#pragma unroll
            for (int r = 0; r < 4; ++r) acc[r] = fmaf(a[r][k], w, acc[r]);
        }
    } else {
        for (int k = k0; k < k0 + 128; ++k)
            acc[0] = fmaf(a[0][k], W2[(size_t)k * OUT_CH + j], acc[0]);
    }
#pragma unroll
    for (int r = 0; r < 4; ++r) red[kc][r][j] = acc[r];
    __syncthreads();
    if (kc == 0) {
#pragma unroll
        for (int r = 0; r < 4; ++r) {
            const float s = red[0][r][j] + red[1][r][j] + red[2][r][j] + red[3][r][j];
            if (!bias) W12t[(size_t)j * IN_CH + blk * 4 + r] = f2bf(s);
            else if (r == 0) b2[j] = s;
        }
    }
}

// ---------------------------------------------------------------------------
// FUSED: blocks 0..3124 convert x->xb (bf16); blocks 3125..3320 partition
// edges into 391 fixed-capacity dst-buckets (128 nodes each).
// Packed word: b<<23 | src<<7 | (dst&127).
// ---------------------------------------------------------------------------
__global__ __launch_bounds__(512) void cvt_part(const float* __restrict__ x,
                                                ushort* __restrict__ xb,
                                                const int* __restrict__ ei,
                                                int* __restrict__ bucketcnt,
                                                uint* __restrict__ pairbuf) {
    __shared__ uint stage[P1_EPB];                 // 16 KB (partition branch only)
    __shared__ int cnt[512], off[512], cur[512], base[512];
    const int t = threadIdx.x;

    if (blockIdx.x < CVT_BLOCKS) {
        const int gid = blockIdx.x * 512 + t;      // 3125*512 == 1.6M exactly
        const float4 v = *(const float4*)(x + (size_t)gid * 4);
        ushort4 o;
        o.x = f2bf(v.x); o.y = f2bf(v.y); o.z = f2bf(v.z); o.w = f2bf(v.w);
        *(ushort4*)(xb + (size_t)gid * 4) = o;
        return;
    }

    const int e0 = (blockIdx.x - CVT_BLOCKS) * P1_EPB;

    cnt[t] = 0;
    __syncthreads();

    uint pk[P1_EPT];
    int  bk[P1_EPT];
    bool vl[P1_EPT];
#pragma unroll
    for (int i = 0; i < P1_EPT; ++i) {
        const int e = e0 + i * 512 + t;
        vl[i] = (e < N_EDGES);
        if (vl[i]) {
            const int src = ei[e];
            const int dst = ei[N_EDGES + e];
            const int b = dst >> BKT_SHIFT;
            bk[i] = b;
            pk[i] = ((uint)b << 23) | ((uint)src << 7) | (uint)(dst & (BKT_NODES - 1));
            atomicAdd(&cnt[b], 1);
        }
    }
    __syncthreads();

    // exclusive scan of cnt[0..511] -> off
    off[t] = cnt[t];
    __syncthreads();
#pragma unroll
    for (int d = 1; d < 512; d <<= 1) {
        const int u = (t >= d) ? off[t - d] : 0;
        __syncthreads();
        off[t] += u;
        __syncthreads();
    }
    off[t] -= cnt[t];                              // exclusive
    cur[t] = off[t];
    if (t < NBKT && cnt[t] > 0)
        base[t] = t * BCAP + atomicAdd(&bucketcnt[t], cnt[t]);
    __syncthreads();

#pragma unroll
    for (int i = 0; i < P1_EPT; ++i)
        if (vl[i]) {
            const int lp = atomicAdd(&cur[bk[i]], 1);
            stage[lp] = pk[i];
        }
    __syncthreads();

    const int TOT = off[511] + cnt[511];
    for (int idx = t; idx < TOT; idx += 512) {
        const uint p = stage[idx];
        const int b = (int)(p >> 23);
        pairbuf[base[b] + (idx - off[b])] = p;
    }
}

// ---------------------------------------------------------------------------
// Per-bucket local counting sort: pairbuf bucket -> bucket-local CSR.
// srcidx stored as ushort (src < 65536).
// ---------------------------------------------------------------------------
__global__ __launch_bounds__(256) void bucket_fill2(const uint* __restrict__ pairbuf,
                                                    const int* __restrict__ bucketcnt,
                                                    int* __restrict__ locrow,
                                                    ushort* __restrict__ srcidx) {
    __shared__ int cnt[128], off[128], cur[128];
    const int b = blockIdx.x;
    const int t = threadIdx.x;
    const int ne = bucketcnt[b];
    const uint* eb = pairbuf + (size_t)b * BCAP;

    if (t < 128) cnt[t] = 0;
    __syncthreads();
    for (int i = t; i < ne; i += 256)
        atomicAdd(&cnt[eb[i] & (BKT_NODES - 1)], 1);
    __syncthreads();

    if (t < 128) off[t] = cnt[t];
    __syncthreads();
#pragma unroll
    for (int d = 1; d < 128; d <<= 1) {
        int u = 0;
        if (t < 128 && t >= d) u = off[t - d];
        __syncthreads();
        if (t < 128 && t >= d) off[t] += u;
        __syncthreads();
    }
    if (t < 128) {
        off[t] -= cnt[t];
        cur[t] = off[t];
        locrow[b * (BKT_NODES + 1) + t] = off[t];
        if (t == 0) locrow[b * (BKT_NODES + 1) + BKT_NODES] = ne;
    }
    __syncthreads();

    for (int i = t; i < ne; i += 256) {
        const uint p = eb[i];
        const int ln  = (int)(p & (BKT_NODES - 1));
        const int pos = atomicAdd(&cur[ln], 1);
        srcidx[(size_t)b * BCAP + pos] = (ushort)((p >> 7) & 0xFFFFu);
    }
}

// ---------------------------------------------------------------------------
// Gather v2: 4-edges-per-load. One wave per node; lanes = (g=lane>>4, q=lane&15).
// Lane (g,q) loads uint4 chunk q (16B) of neighbor (e+g)'s row -> one
// global_load_dwordx4 covers 4 neighbor rows (1 KB). Final cross-group
// __shfl_xor(16,32) reduce; self added once post-reduce; 4B/lane writeback.
// ---------------------------------------------------------------------------
__global__ __launch_bounds__(256) void gather_bf16(const ushort* __restrict__ xb,
                                                   const int* __restrict__ locrow,
                                                   const ushort* __restrict__ srcidx,
                                                   ushort* __restrict__ aggb) {
    const int node = (int)((blockIdx.x * 256u + threadIdx.x) >> 6);
    const int lane = threadIdx.x & 63;
    if (node >= N_NODES) return;
    const int g = lane >> 4;                       // edge slot 0..3
    const int q = lane & 15;                       // row chunk 0..15
    const int b  = node >> BKT_SHIFT;
    const int ln = node & (BKT_NODES - 1);
    const uint4* xrow4 = (const uint4*)xb;         // 16 uint4 per 256B row
    int e = locrow[b * (BKT_NODES + 1) + ln];
    const int end = locrow[b * (BKT_NODES + 1) + ln + 1];
    const ushort* sb = srcidx + (size_t)b * BCAP;

    float acc[8] = {0.f, 0.f, 0.f, 0.f, 0.f, 0.f, 0.f, 0.f};
#define ACCUM(vv)                                                      \
    {                                                                  \
        acc[0] += __uint_as_float((vv).x << 16);                       \
        acc[1] += __uint_as_float((vv).x & 0xffff0000u);               \
        acc[2] += __uint_as_float((vv).y << 16);                       \
        acc[3] += __uint_as_float((vv).y & 0xffff0000u);               \
        acc[4] += __uint_as_float((vv).z << 16);                       \
        acc[5] += __uint_as_float((vv).z & 0xffff0000u);               \
        acc[6] += __uint_as_float((vv).w << 16);                       \
        acc[7] += __uint_as_float((vv).w & 0xffff0000u);               \
    }

    for (; e + 8 <= end; e += 8) {                 // 8 edges: 2 dwordx4 in flight
        const int s0 = sb[e + g];
        const int s1 = sb[e + 4 + g];
        const uint4 v0 = xrow4[(size_t)s0 * 16 + q];
        const uint4 v1 = xrow4[(size_t)s1 * 16 + q];
        ACCUM(v0);
        ACCUM(v1);
    }
    for (; e + 4 <= end; e += 4) {
        const int s = sb[e + g];
        const uint4 v = xrow4[(size_t)s * 16 + q];
        ACCUM(v);
    }
    if (e + g < end) {                             // tail 1..3 edges (exec-masked)
        const int s = sb[e + g];
        const uint4 v = xrow4[(size_t)s * 16 + q];
        ACCUM(v);
    }
#undef ACCUM

    // reduce across the 4 edge-slots (lanes differing in bits 4,5)
#pragma unroll
    for (int i = 0; i < 8; ++i) {
        acc[i] += __shfl_xor(acc[i], 16);
        acc[i] += __shfl_xor(acc[i], 32);
    }

    // add self once; lane (g,q) owns output uint q*4+g
    const uint self = ((const uint*)xb)[(size_t)node * 64 + q * 4 + g];
    const float ax = acc[2 * g]     + __uint_as_float(self << 16);
    const float ay = acc[2 * g + 1] + __uint_as_float(self & 0xffff0000u);
    ((uint*)aggb)[(size_t)node * 64 + q * 4 + g] =
        ((uint)f2bf(ay) << 16) | (uint)f2bf(ax);
}

// ---------------------------------------------------------------------------
// out[50000,256] = aggb @ W12 + b2 via bf16 MFMA 16x16x32.
// BM=128 -> 391 blocks (full CU coverage). Nontemporal stores.
// ---------------------------------------------------------------------------
__global__ __launch_bounds__(512) void mfma_gemm(const ushort* __restrict__ aggb,
                                                 const ushort* __restrict__ w12t,
                                                 const float* __restrict__ b2,
                                                 float* __restrict__ out) {
    __shared__ ushort bt[256 * 128];               // 64 KB
    const int tid = threadIdx.x;

#pragma unroll
    for (int it = 0; it < 8; ++it) {
        const int i = tid + it * 512;              // 0..4095
        const int n = i >> 4, s = i & 15;
        const uint4 v = *(const uint4*)(w12t + (size_t)i * 8);
        *(uint4*)(&bt[(n << 7) + ((s ^ (n & 7)) << 3)]) = v;
    }
    __syncthreads();

    const int lane = tid & 63;
    const int w    = tid >> 6;
    const int rbase = blockIdx.x * 128 + (w >> 1) * 32;
    const int cbase = (w & 1) * 128;
    const int l15 = lane & 15;
    const int oct = lane >> 4;

    f32x4 acc[2][8];
#pragma unroll
    for (int m = 0; m < 2; ++m)
#pragma unroll
        for (int n = 0; n < 8; ++n)
            acc[m][n] = (f32x4){0.f, 0.f, 0.f, 0.f};

#pragma unroll
    for (int kk = 0; kk < 4; ++kk) {               // k = kk*32 + oct*8 + j
        bf16x8 afr[2];
#pragma unroll
        for (int m = 0; m < 2; ++m) {
            int row = rbase + m * 16 + l15;
            row = row < N_NODES ? row : N_NODES - 1;
            afr[m] = *(const bf16x8*)(aggb + (size_t)row * IN_CH + kk * 32 + oct * 8);
        }
#pragma unroll
        for (int n = 0; n < 8; ++n) {
            const int col  = cbase + n * 16 + l15;
            const int slot = (kk * 4 + oct) ^ (col & 7);
            const bf16x8 bfr = *(const bf16x8*)(&bt[(col << 7) + (slot << 3)]);
#pragma unroll
            for (int m = 0; m < 2; ++m)
                acc[m][n] = __builtin_amdgcn_mfma_f32_16x16x32_bf16(
                    afr[m], bfr, acc[m][n], 0, 0, 0);
        }
    }

#pragma unroll
    for (int m = 0; m < 2; ++m) {
        const int row0 = rbase + m * 16 + oct * 4;
#pragma unroll
        for (int n = 0; n < 8; ++n) {
            const int col = cbase + n * 16 + l15;
            const float bias = b2[col];
#pragma unroll
            for (int r = 0; r < 4; ++r) {
                const int row = row0 + r;
                if (row < N_NODES)
                    __builtin_nontemporal_store(acc[m][n][r] + bias,
                                                &out[(size_t)row * OUT_CH + col]);
            }
        }
    }
}

// ---------------------------------------------------------------------------
extern "C" void kernel_launch(void* const* d_in, const int* in_sizes, int n_in,
                              void* d_out, int out_size, void* d_ws, size_t ws_size,
                              hipStream_t stream) {
    const float* x  = (const float*)d_in[0];
    const int*   ei = (const int*)d_in[1];      // [2, N_EDGES] int32
    const float* W1 = (const float*)d_in[2];
    const float* b1 = (const float*)d_in[3];
    const float* W2 = (const float*)d_in[4];
    float* out = (float*)d_out;

    // workspace layout (bytes)
    char* ws = (char*)d_ws;
    ushort* xb        = (ushort*)(ws + 0);               // 12,800,000
    ushort* aggb      = (ushort*)(ws + 12800000);        // 12,800,000
    uint*   pairbuf   = (uint*)  (ws + 12800000);        //  6,406,144 (aliases aggb;
                                                         //   dead before gather runs)
    ushort* W12t      = (ushort*)(ws + 25600000);        //     65,536
    float*  b2        = (float*) (ws + 25665536);        //      1,024
    ushort* srcidx    = (ushort*)(ws + 25666560);        //  3,203,072 (391*4096*2)
    int*    locrow    = (int*)   (ws + 28869632);        //    201,756 (391*129*4)
    int*    bucketcnt = (int*)   (ws + 29071388);        //      1,564  -> ~29.1 MB

    // 1) collapse MLP -> bf16 W12^T + f32 b2 (+ zero bucketcnt)
    build_w12<<<dim3(33), dim3(1024), 0, stream>>>(W1, b1, W2, W12t, b2, bucketcnt);

    // 2) FUSED: x -> bf16 || partition edges into dst-buckets
    cvt_part<<<dim3(CVT_BLOCKS + P1_BLOCKS), dim3(512), 0, stream>>>(
        x, xb, ei, bucketcnt, pairbuf);

    // 3) per-bucket local counting sort -> bucket-local CSR (ushort srcs)
    bucket_fill2<<<dim3(NBKT), dim3(256), 0, stream>>>(pairbuf, bucketcnt,
                                                       locrow, srcidx);

    // 4) gather v2 (4 edges/load, residual folded): aggb = x + scatter-sum
    gather_bf16<<<dim3(N_NODES * 64 / 256), dim3(256), 0, stream>>>(
        xb, locrow, srcidx, aggb);

    // 5) out = aggb @ W12 + b2   (bf16 MFMA)
    mfma_gemm<<<dim3((N_NODES + 127) / 128), dim3(512), 0, stream>>>(
        aggb, W12t, b2, out);
}

// Round 16
// 85.081 us; speedup vs baseline: 1.6212x; 1.0159x over previous
//
#include <hip/hip_runtime.h>

#define N_NODES 50000
#define N_EDGES 800000
#define IN_CH   128
#define HID_CH  512
#define OUT_CH  256

// 128-node dst-buckets, fixed capacity (mean 2048, sigma~45, cap 4096)
#define BKT_SHIFT 7
#define BKT_NODES 128
#define NBKT ((N_NODES + BKT_NODES - 1) / BKT_NODES)        // 391
#define BCAP 4096
#define P1_EPT    8
#define P1_EPB    (512 * P1_EPT)                            // 4096 edges/block
#define P1_BLOCKS ((N_EDGES + P1_EPB - 1) / P1_EPB)         // 196
#define CVT_BLOCKS 3125                                     // 1.6M float4 / 512

typedef __attribute__((ext_vector_type(8))) short bf16x8;
typedef __attribute__((ext_vector_type(4))) float f32x4;

static __device__ __forceinline__ ushort f2bf(float f) {
    uint u = __float_as_uint(f);
    uint r = u + 0x7fffu + ((u >> 16) & 1u);   // RNE; inputs are finite
    return (ushort)(r >> 16);
}

// inclusive scan of v across the 64-lane wave
static __device__ __forceinline__ int wave_iscan(int v, int lane) {
#pragma unroll
    for (int d = 1; d < 64; d <<= 1) {
        const int u = __shfl_up(v, d);
        if (lane >= d) v += u;
    }
    return v;
}

// ---------------------------------------------------------------------------
// W12t[j][i] = sum_k W1[i][k]*W2[k][j]  (bf16, TRANSPOSED [256][128])
// b2[j] = sum_k b1[k]*W2[k][j]          (f32)
// 33 blocks x 1024 thr; block 0 also zeroes bucketcnt.
// ---------------------------------------------------------------------------
__global__ __launch_bounds__(1024) void build_w12(const float* __restrict__ W1,
                                                  const float* __restrict__ b1,
                                                  const float* __restrict__ W2,
                                                  ushort* __restrict__ W12t,
                                                  float* __restrict__ b2,
                                                  int* __restrict__ bucketcnt) {
    __shared__ float a[4][HID_CH];                 // 8 KB
    __shared__ float red[4][4][256];               // 16 KB  [kc][row][j]
    const int t   = threadIdx.x;
    const int j   = t & 255;
    const int kc  = t >> 8;                        // 0..3
    const int blk = blockIdx.x;
    if (blk == 0 && t < NBKT) bucketcnt[t] = 0;

    const bool bias = (blk == 32);
    if (!bias) {
        const int i0 = blk * 4;
        for (int lin = t; lin < 4 * HID_CH; lin += 1024)
            a[lin >> 9][lin & 511] = W1[(size_t)(i0 + (lin >> 9)) * HID_CH + (lin & 511)];
    } else {
        for (int lin = t; lin < HID_CH; lin += 1024) a[0][lin] = b1[lin];
    }
    __syncthreads();

    float acc[4] = {0.f, 0.f, 0.f, 0.f};
    const int k0 = kc * 128;
    if (!bias) {
        for (int k = k0; k < k0 + 128; ++k) {
            const float w = W2[(size_t)k * OUT_CH + j];
#pragma unroll
            for (int r = 0; r < 4; ++r) acc[r] = fmaf(a[r][k], w, acc[r]);
        }
    } else {
        for (int k = k0; k < k0 + 128; ++k)
            acc[0] = fmaf(a[0][k], W2[(size_t)k * OUT_CH + j], acc[0]);
    }
#pragma unroll
    for (int r = 0; r < 4; ++r) red[kc][r][j] = acc[r];
    __syncthreads();
    if (kc == 0) {
#pragma unroll
        for (int r = 0; r < 4; ++r) {
            const float s = red[0][r][j] + red[1][r][j] + red[2][r][j] + red[3][r][j];
            if (!bias) W12t[(size_t)j * IN_CH + blk * 4 + r] = f2bf(s);
            else if (r == 0) b2[j] = s;
        }
    }
}

// ---------------------------------------------------------------------------
// FUSED: blocks 0..3124 convert x->xb (bf16); blocks 3125..3320 partition
// edges into 391 fixed-capacity dst-buckets (128 nodes each).
// Packed word: b<<23 | src<<7 | (dst&127). Scan via wave shuffles (2 barriers).
// ---------------------------------------------------------------------------
__global__ __launch_bounds__(512) void cvt_part(const float* __restrict__ x,
                                                ushort* __restrict__ xb,
                                                const int* __restrict__ ei,
                                                int* __restrict__ bucketcnt,
                                                uint* __restrict__ pairbuf) {
    __shared__ uint stage[P1_EPB];                 // 16 KB (partition branch only)
    __shared__ int cnt[512], off[512], cur[512], base[512];
    __shared__ int wsum[8], wexc[8];
    const int t = threadIdx.x;

    if (blockIdx.x < CVT_BLOCKS) {
        const int gid = blockIdx.x * 512 + t;      // 3125*512 == 1.6M exactly
        const float4 v = *(const float4*)(x + (size_t)gid * 4);
        ushort4 o;
        o.x = f2bf(v.x); o.y = f2bf(v.y); o.z = f2bf(v.z); o.w = f2bf(v.w);
        *(ushort4*)(xb + (size_t)gid * 4) = o;
        return;
    }

    const int e0 = (blockIdx.x - CVT_BLOCKS) * P1_EPB;

    cnt[t] = 0;
    __syncthreads();

    uint pk[P1_EPT];
    int  bk[P1_EPT];
    bool vl[P1_EPT];
#pragma unroll
    for (int i = 0; i < P1_EPT; ++i) {
        const int e = e0 + i * 512 + t;
        vl[i] = (e < N_EDGES);
        if (vl[i]) {
            const int src = ei[e];
            const int dst = ei[N_EDGES + e];
            const int b = dst >> BKT_SHIFT;
            bk[i] = b;
            pk[i] = ((uint)b << 23) | ((uint)src << 7) | (uint)(dst & (BKT_NODES - 1));
            atomicAdd(&cnt[b], 1);
        }
    }
    __syncthreads();

    // exclusive scan of cnt[0..511] via wave shuffles
    const int lane = t & 63;
    const int wv   = t >> 6;
    const int v = cnt[t];
    const int w = wave_iscan(v, lane);
    if (lane == 63) wsum[wv] = w;
    __syncthreads();
    if (t < 8) {
        int s = 0;
        for (int i = 0; i < t; ++i) s += wsum[i];
        wexc[t] = s;
    }
    __syncthreads();
    const int exc = w - v + wexc[wv];
    off[t] = exc;
    cur[t] = exc;
    if (t < NBKT && v > 0)
        base[t] = t * BCAP + atomicAdd(&bucketcnt[t], v);
    __syncthreads();

#pragma unroll
    for (int i = 0; i < P1_EPT; ++i)
        if (vl[i]) {
            const int lp = atomicAdd(&cur[bk[i]], 1);
            stage[lp] = pk[i];
        }
    __syncthreads();

    const int TOT = off[511] + cnt[511];
    for (int idx = t; idx < TOT; idx += 512) {
        const uint p = stage[idx];
        const int b = (int)(p >> 23);
        pairbuf[base[b] + (idx - off[b])] = p;
    }
}

// ---------------------------------------------------------------------------
// Per-bucket local counting sort: pairbuf bucket -> bucket-local CSR.
// srcidx stored as ushort. Scan via wave shuffles (1 barrier).
// ---------------------------------------------------------------------------
__global__ __launch_bounds__(256) void bucket_fill2(const uint* __restrict__ pairbuf,
                                                    const int* __restrict__ bucketcnt,
                                                    int* __restrict__ locrow,
                                                    ushort* __restrict__ srcidx) {
    __shared__ int cnt[128], off[128], cur[128];
    __shared__ int ws2[2];
    const int b = blockIdx.x;
    const int t = threadIdx.x;
    const int ne = bucketcnt[b];
    const uint* eb = pairbuf + (size_t)b * BCAP;

    if (t < 128) cnt[t] = 0;
    __syncthreads();
    for (int i = t; i < ne; i += 256)
        atomicAdd(&cnt[eb[i] & (BKT_NODES - 1)], 1);
    __syncthreads();

    const int lane = t & 63;
    const int v = (t < 128) ? cnt[t] : 0;
    const int w = wave_iscan(v, lane);
    if (t < 128 && lane == 63) ws2[t >> 6] = w;
    __syncthreads();
    if (t < 128) {
        const int exc = w - v + ((t >= 64) ? ws2[0] : 0);
        off[t] = exc;
        cur[t] = exc;
        locrow[b * (BKT_NODES + 1) + t] = exc;
        if (t == 0) locrow[b * (BKT_NODES + 1) + BKT_NODES] = ne;
    }
    __syncthreads();

    for (int i = t; i < ne; i += 256) {
        const uint p = eb[i];
        const int ln  = (int)(p & (BKT_NODES - 1));
        const int pos = atomicAdd(&cur[ln], 1);
        srcidx[(size_t)b * BCAP + pos] = (ushort)((p >> 7) & 0xFFFFu);
    }
}

// ---------------------------------------------------------------------------
// Gather v3: 4-edges-per-load, 16 edges (4x dwordx4) in flight.
// One wave per node; lanes = (g=lane>>4, q=lane&15). Lane (g,q) loads uint4
// chunk q of neighbor (e+4i+g)'s row. Final __shfl_xor(16,32) reduce.
// ---------------------------------------------------------------------------
__global__ __launch_bounds__(256) void gather_bf16(const ushort* __restrict__ xb,
                                                   const int* __restrict__ locrow,
                                                   const ushort* __restrict__ srcidx,
                                                   ushort* __restrict__ aggb) {
    const int node = (int)((blockIdx.x * 256u + threadIdx.x) >> 6);
    const int lane = threadIdx.x & 63;
    if (node >= N_NODES) return;
    const int g = lane >> 4;                       // edge slot 0..3
    const int q = lane & 15;                       // row chunk 0..15
    const int b  = node >> BKT_SHIFT;
    const int ln = node & (BKT_NODES - 1);
    const uint4* xrow4 = (const uint4*)xb;         // 16 uint4 per 256B row
    int e = locrow[b * (BKT_NODES + 1) + ln];
    const int end = locrow[b * (BKT_NODES + 1) + ln + 1];
    const ushort* sb = srcidx + (size_t)b * BCAP;

    float acc[8] = {0.f, 0.f, 0.f, 0.f, 0.f, 0.f, 0.f, 0.f};
#define ACCUM(vv)                                                      \
    {                                                                  \
        acc[0] += __uint_as_float((vv).x << 16);                       \
        acc[1] += __uint_as_float((vv).x & 0xffff0000u);               \
        acc[2] += __uint_as_float((vv).y << 16);                       \
        acc[3] += __uint_as_float((vv).y & 0xffff0000u);               \
        acc[4] += __uint_as_float((vv).z << 16);                       \
        acc[5] += __uint_as_float((vv).z & 0xffff0000u);               \
        acc[6] += __uint_as_float((vv).w << 16);                       \
        acc[7] += __uint_as_float((vv).w & 0xffff0000u);               \
    }

    for (; e + 16 <= end; e += 16) {               // 16 edges: 4 dwordx4 in flight
        const int s0 = sb[e + g];
        const int s1 = sb[e + 4 + g];
        const int s2 = sb[e + 8 + g];
        const int s3 = sb[e + 12 + g];
        const uint4 v0 = xrow4[(size_t)s0 * 16 + q];
        const uint4 v1 = xrow4[(size_t)s1 * 16 + q];
        const uint4 v2 = xrow4[(size_t)s2 * 16 + q];
        const uint4 v3 = xrow4[(size_t)s3 * 16 + q];
        ACCUM(v0);
        ACCUM(v1);
        ACCUM(v2);
        ACCUM(v3);
    }
    for (; e + 8 <= end; e += 8) {
        const int s0 = sb[e + g];
        const int s1 = sb[e + 4 + g];
        const uint4 v0 = xrow4[(size_t)s0 * 16 + q];
        const uint4 v1 = xrow4[(size_t)s1 * 16 + q];
        ACCUM(v0);
        ACCUM(v1);
    }
    for (; e + 4 <= end; e += 4) {
        const int s = sb[e + g];
        const uint4 v = xrow4[(size_t)s * 16 + q];
        ACCUM(v);
    }
    if (e + g < end) {                             // tail 1..3 edges (exec-masked)
        const int s = sb[e + g];
        const uint4 v = xrow4[(size_t)s * 16 + q];
        ACCUM(v);
    }
#undef ACCUM

    // reduce across the 4 edge-slots (lanes differing in bits 4,5)
#pragma unroll
    for (int i = 0; i < 8; ++i) {
        acc[i] += __shfl_xor(acc[i], 16);
        acc[i] += __shfl_xor(acc[i], 32);
    }

    // add self once; lane (g,q) owns output uint q*4+g
    const uint self = ((const uint*)xb)[(size_t)node * 64 + q * 4 + g];
    const float ax = acc[2 * g]     + __uint_as_float(self << 16);
    const float ay = acc[2 * g + 1] + __uint_as_float(self & 0xffff0000u);
    ((uint*)aggb)[(size_t)node * 64 + q * 4 + g] =
        ((uint)f2bf(ay) << 16) | (uint)f2bf(ax);
}

// ---------------------------------------------------------------------------
// out[50000,256] = aggb @ W12 + b2 via bf16 MFMA 16x16x32.
// BM=128 -> 391 blocks (full CU coverage). Nontemporal stores.
// ---------------------------------------------------------------------------
__global__ __launch_bounds__(512) void mfma_gemm(const ushort* __restrict__ aggb,
                                                 const ushort* __restrict__ w12t,
                                                 const float* __restrict__ b2,
                                                 float* __restrict__ out) {
    __shared__ ushort bt[256 * 128];               // 64 KB
    const int tid = threadIdx.x;

#pragma unroll
    for (int it = 0; it < 8; ++it) {
        const int i = tid + it * 512;              // 0..4095
        const int n = i >> 4, s = i & 15;
        const uint4 v = *(const uint4*)(w12t + (size_t)i * 8);
        *(uint4*)(&bt[(n << 7) + ((s ^ (n & 7)) << 3)]) = v;
    }
    __syncthreads();

    const int lane = tid & 63;
    const int w    = tid >> 6;
    const int rbase = blockIdx.x * 128 + (w >> 1) * 32;
    const int cbase = (w & 1) * 128;
    const int l15 = lane & 15;
    const int oct = lane >> 4;

    f32x4 acc[2][8];
#pragma unroll
    for (int m = 0; m < 2; ++m)
#pragma unroll
        for (int n = 0; n < 8; ++n)
            acc[m][n] = (f32x4){0.f, 0.f, 0.f, 0.f};

#pragma unroll
    for (int kk = 0; kk < 4; ++kk) {               // k = kk*32 + oct*8 + j
        bf16x8 afr[2];
#pragma unroll
        for (int m = 0; m < 2; ++m) {
            int row = rbase + m * 16 + l15;
            row = row < N_NODES ? row : N_NODES - 1;
            afr[m] = *(const bf16x8*)(aggb + (size_t)row * IN_CH + kk * 32 + oct * 8);
        }
#pragma unroll
        for (int n = 0; n < 8; ++n) {
            const int col  = cbase + n * 16 + l15;
            const int slot = (kk * 4 + oct) ^ (col & 7);
            const bf16x8 bfr = *(const bf16x8*)(&bt[(col << 7) + (slot << 3)]);
#pragma unroll
            for (int m = 0; m < 2; ++m)
                acc[m][n] = __builtin_amdgcn_mfma_f32_16x16x32_bf16(
                    afr[m], bfr, acc[m][n], 0, 0, 0);
        }
    }

#pragma unroll
    for (int m = 0; m < 2; ++m) {
        const int row0 = rbase + m * 16 + oct * 4;
#pragma unroll
        for (int n = 0; n < 8; ++n) {
            const int col = cbase + n * 16 + l15;
            const float bias = b2[col];
#pragma unroll
            for (int r = 0; r < 4; ++r) {
                const int row = row0 + r;
                if (row < N_NODES)
                    __builtin_nontemporal_store(acc[m][n][r] + bias,
                                                &out[(size_t)row * OUT_CH + col]);
            }
        }
    }
}

// ---------------------------------------------------------------------------
extern "C" void kernel_launch(void* const* d_in, const int* in_sizes, int n_in,
                              void* d_out, int out_size, void* d_ws, size_t ws_size,
                              hipStream_t stream) {
    const float* x  = (const float*)d_in[0];
    const int*   ei = (const int*)d_in[1];      // [2, N_EDGES] int32
    const float* W1 = (const float*)d_in[2];
    const float* b1 = (const float*)d_in[3];
    const float* W2 = (const float*)d_in[4];
    float* out = (float*)d_out;

    // workspace layout (bytes)
    char* ws = (char*)d_ws;
    ushort* xb        = (ushort*)(ws + 0);               // 12,800,000
    ushort* aggb      = (ushort*)(ws + 12800000);        // 12,800,000
    uint*   pairbuf   = (uint*)  (ws + 12800000);        //  6,406,144 (aliases aggb;
                                                         //   dead before gather runs)
    ushort* W12t      = (ushort*)(ws + 25600000);        //     65,536
    float*  b2        = (float*) (ws + 25665536);        //      1,024
    ushort* srcidx    = (ushort*)(ws + 25666560);        //  3,203,072 (391*4096*2)
    int*    locrow    = (int*)   (ws + 28869632);        //    201,756 (391*129*4)
    int*    bucketcnt = (int*)   (ws + 29071388);        //      1,564  -> ~29.1 MB

    // 1) collapse MLP -> bf16 W12^T + f32 b2 (+ zero bucketcnt)
    build_w12<<<dim3(33), dim3(1024), 0, stream>>>(W1, b1, W2, W12t, b2, bucketcnt);

    // 2) FUSED: x -> bf16 || partition edges into dst-buckets
    cvt_part<<<dim3(CVT_BLOCKS + P1_BLOCKS), dim3(512), 0, stream>>>(
        x, xb, ei, bucketcnt, pairbuf);

    // 3) per-bucket local counting sort -> bucket-local CSR (ushort srcs)
    bucket_fill2<<<dim3(NBKT), dim3(256), 0, stream>>>(pairbuf, bucketcnt,
                                                       locrow, srcidx);

    // 4) gather v3 (16 edges in flight, residual folded): aggb = x + scatter-sum
    gather_bf16<<<dim3(N_NODES * 64 / 256), dim3(256), 0, stream>>>(
        xb, locrow, srcidx, aggb);

    // 5) out = aggb @ W12 + b2   (bf16 MFMA)
    mfma_gemm<<<dim3((N_NODES + 127) / 128), dim3(512), 0, stream>>>(
        aggb, W12t, b2, out);
}